// Round 2
// baseline (844.399 us; speedup 1.0000x reference)
//
#include <hip/hip_runtime.h>
#include <cstdint>
#include <cstddef>

#define E_ 8
#define T_ 1024
#define D_ 1024
#define I_ 5632
#define TWO_I_ 11264
#define NPAD_MAX 2176                 /* 2048 + 8*16 */
#define NGRP_MAX 136

// ws layout (bytes): int tables in [0,64K), then act_f, then xg_f, y overlays xg_f
#define WS_ACTF_B 65536
#define WS_XGF_B  (65536 + 24510464)              /* act_f = 136*180224      */
#define WS_Y_B    WS_XGF_B                        /* y overlays dead xg_f    */
// int-table offsets (units of 4 B)
#define WS_CNT   0
#define WS_BASEP 8
#define WS_ESLOT 16
#define WS_TOKW  2064
#define WS_ETOK  4112

typedef __attribute__((ext_vector_type(8))) __bf16 bf16x8;
typedef __attribute__((ext_vector_type(4))) float  f32x4;

__device__ __forceinline__ unsigned f2bf(float f) {
    unsigned u = __float_as_uint(f);
    u += 0x7fffu + ((u >> 16) & 1u);
    return u >> 16;
}
__device__ __forceinline__ unsigned pack2bf(float f0, float f1) {
    unsigned a0 = __float_as_uint(f0); a0 += 0x7fffu + ((a0 >> 16) & 1u);
    unsigned a1 = __float_as_uint(f1); a1 += 0x7fffu + ((a1 >> 16) & 1u);
    return (a0 >> 16) | (a1 & 0xffff0000u);
}

// ---------------------------------------------------------------- routing ---
__global__ void routing_kernel(const float* __restrict__ gate,
                               int* cnt, int* basep, int* eslot,
                               float* tokw, int* etok)
{
    int t = threadIdx.x;
    if (t < E_) cnt[t] = 0;
    __syncthreads();
    float g[E_];
#pragma unroll
    for (int e = 0; e < E_; ++e) g[e] = gate[t * E_ + e];
    int i0 = 0; float p0 = g[0];
#pragma unroll
    for (int e = 1; e < E_; ++e) if (g[e] > p0) { p0 = g[e]; i0 = e; }
    int i1 = -1; float p1 = -1e30f;
#pragma unroll
    for (int e = 0; e < E_; ++e) if (e != i0 && g[e] > p1) { p1 = g[e]; i1 = e; }
    float w0 = 1.0f / (1.0f + expf(p1 - p0));
    float w1 = 1.0f - w0;
    int s0 = atomicAdd(&cnt[i0], 1);
    int s1 = atomicAdd(&cnt[i1], 1);
    etok[i0 * T_ + s0] = t;
    etok[i1 * T_ + s1] = t;
    eslot[t * 2 + 0] = i0 * T_ + s0;  tokw[t * 2 + 0] = w0;
    eslot[t * 2 + 1] = i1 * T_ + s1;  tokw[t * 2 + 1] = w1;
    __syncthreads();
    if (t == 0) {
        int r = 0;
#pragma unroll
        for (int e = 0; e < E_; ++e) { basep[e] = r; r += (cnt[e] + 15) & ~15; }
    }
}

// ------------------- gather x rows, cast bf16, fragment-major swizzle -------
__global__ void gather_cast_kernel(const float* __restrict__ x,
                                   const int* __restrict__ cnt,
                                   const int* __restrict__ basep,
                                   const int* __restrict__ etok,
                                   unsigned short* __restrict__ xgf)
{
    int e = blockIdx.x >> 6, g = blockIdx.x & 63;
    int n = cnt[e];
    if (g * 16 >= n) return;
    int tid = threadIdx.x;
    int row = g * 16 + (tid & 15);
    row = min(row, n - 1);
    int tok = etok[e * T_ + row];
    const float* xr = x + (size_t)tok * D_;
    unsigned short* dst = xgf + ((size_t)(basep[e] >> 4) + g) * 16384;
#pragma unroll
    for (int it = 0; it < 8; ++it) {
        int c = it * 16 + (tid >> 4);          // k-chunk 0..127
        float4 v0 = *(const float4*)(xr + c * 8);
        float4 v1 = *(const float4*)(xr + c * 8 + 4);
        uint4 h;
        h.x = pack2bf(v0.x, v0.y); h.y = pack2bf(v0.z, v0.w);
        h.z = pack2bf(v1.x, v1.y); h.w = pack2bf(v1.z, v1.w);
        *(uint4*)(dst + c * 128 + (tid & 15) * 8) = h;
    }
}

// ------------------------------------------------- gemm1: xg@w1 + silu -----
// grid = E_*176, block 4 waves. B path: LDS-staged transpose+dequant with
// RAW s_barrier + counted waits (T3/T4): vmcnt is NEVER drained, so the
// 2-stage-deep global B prefetch stays in flight across barriers (the
// __syncthreads vmcnt(0) drain was the round-1 limiter). Stage = 2 K-steps
// (BK=64), 2x8KB LDS double buffer, one barrier per stage. A loads are
// issued BEFORE the B prefetch so their counted vmcnt waits leave the
// prefetch outstanding. s_setprio around the MFMA cluster (T5).
__global__ __launch_bounds__(256, 2) void gemm1_kernel(
    const unsigned short* __restrict__ xgf, const int* __restrict__ w1q,
    const float* __restrict__ w1s, const int* __restrict__ cnt,
    const int* __restrict__ basep, unsigned short* __restrict__ actf)
{
    __shared__ unsigned char blds[16384];
    int cg = blockIdx.x % 176, e = blockIdx.x / 176;
    int n = cnt[e];
    if (n <= 0) return;
    int npad = (n + 15) & ~15;
    int pb = basep[e];
    int tid = threadIdx.x, lane = tid & 63, w = tid >> 6;
    int l15 = lane & 15, lq = lane >> 4;
    int colg = w & 1, mh = w >> 1;
    int jcol = cg * 32 + colg * 16 + l15;

    // staging-side role: thread -> (column, k-subgroup)
    int col64 = tid & 63, kg = tid >> 6;
    int jb = (col64 < 32) ? (cg * 32 + col64) : (I_ + cg * 32 + (col64 - 32));
    const int*   gq  = w1q + ((size_t)e * 1024 + kg * 8) * TWO_I_ + jb;
    const float* sqp = w1s + (size_t)e * 8 * TWO_I_ + jb;
    // LDS fragment layout (per 4KB k-step slot): [c=col64/16][lane'][j]
    unsigned swr = (unsigned)(col64 >> 4) * 1024 + (unsigned)(kg * 16 + (col64 & 15)) * 16;
    unsigned srd = (unsigned)colg * 1024 + (unsigned)lane * 16;   // gate; up at +2048

    int PA[16], PB[16];
    float sc = 0.f, oc = 0.f;

#define G1_ISSUE2(T, P)                                                     \
    { _Pragma("unroll")                                                     \
      for (int i_ = 0; i_ < 8; ++i_)                                        \
          P[i_] = gq[(size_t)((T) * 64 + i_) * TWO_I_];                     \
      _Pragma("unroll")                                                     \
      for (int i_ = 0; i_ < 8; ++i_)                                        \
          P[8 + i_] = gq[(size_t)((T) * 64 + 32 + i_) * TWO_I_]; }

#define G1_DEQW1(KS, P, O)                                                  \
    { if (((KS) & 3) == 0) { sc = sqp[(size_t)((KS) >> 2) * TWO_I_];        \
                             oc = -8.f * sc; }                              \
      uint4 fr_;                                                            \
      fr_.x = pack2bf((float)P[(O)+0]*sc + oc, (float)P[(O)+1]*sc + oc);    \
      fr_.y = pack2bf((float)P[(O)+2]*sc + oc, (float)P[(O)+3]*sc + oc);    \
      fr_.z = pack2bf((float)P[(O)+4]*sc + oc, (float)P[(O)+5]*sc + oc);    \
      fr_.w = pack2bf((float)P[(O)+6]*sc + oc, (float)P[(O)+7]*sc + oc);    \
      *(uint4*)(&blds[((((KS) >> 1) & 1) * 8192) + (((KS) & 1) * 4096)      \
                      + swr]) = fr_; }

#define G1_DEQW2(T, P)  { G1_DEQW1((2*(T)), P, 0) G1_DEQW1((2*(T)+1), P, 8) }

    for (int tb = 0; tb < npad; tb += 320) {
        int aoff[10];
#pragma unroll
        for (int mi = 0; mi < 10; ++mi) {
            int R = tb + mh * 160 + mi * 16;
            R = min(R, npad - 16);
            aoff[mi] = ((pb + R) >> 4) * 32768;
        }
        const char* abase = (const char*)xgf + lq * 256 + l15 * 16;

        f32x4 accg[10], accu[10];
#pragma unroll
        for (int mi = 0; mi < 10; ++mi) {
            accg[mi] = (f32x4){0.f, 0.f, 0.f, 0.f};
            accu[mi] = (f32x4){0.f, 0.f, 0.f, 0.f};
        }
        G1_ISSUE2(0, PA);
        G1_ISSUE2(1, PB);
        G1_DEQW2(0, PA);
        G1_ISSUE2(2, PA);
        asm volatile("s_waitcnt lgkmcnt(0)" ::: "memory");
        __builtin_amdgcn_s_barrier();
        asm volatile("" ::: "memory");

#pragma unroll 1
        for (int s2 = 0; s2 < 8; ++s2) {
            // ---------- even stage s = 2*s2 : read buf0 ----------
            {
                const char* at = abase + (size_t)s2 * 4096;
                bf16x8 a0[10], a1[10];
#pragma unroll
                for (int mi = 0; mi < 10; ++mi)
                    a0[mi] = *(const bf16x8*)(at + aoff[mi]);
#pragma unroll
                for (int mi = 0; mi < 10; ++mi)
                    a1[mi] = *(const bf16x8*)(at + 1024 + aoff[mi]);
                bf16x8 bg0 = *(const bf16x8*)(&blds[srd]);
                bf16x8 bu0 = *(const bf16x8*)(&blds[srd + 2048]);
                bf16x8 bg1 = *(const bf16x8*)(&blds[4096 + srd]);
                bf16x8 bu1 = *(const bf16x8*)(&blds[4096 + srd + 2048]);
                G1_DEQW2(2*s2 + 1, PB);
                if (s2 < 7) { G1_ISSUE2(2*s2 + 3, PB); }
                asm volatile("s_waitcnt lgkmcnt(0)" ::: "memory");
                __builtin_amdgcn_sched_barrier(0);
                __builtin_amdgcn_s_setprio(1);
#pragma unroll
                for (int mi = 0; mi < 10; ++mi) {
                    accg[mi] = __builtin_amdgcn_mfma_f32_16x16x32_bf16(a0[mi], bg0, accg[mi], 0, 0, 0);
                    accu[mi] = __builtin_amdgcn_mfma_f32_16x16x32_bf16(a0[mi], bu0, accu[mi], 0, 0, 0);
                }
#pragma unroll
                for (int mi = 0; mi < 10; ++mi) {
                    accg[mi] = __builtin_amdgcn_mfma_f32_16x16x32_bf16(a1[mi], bg1, accg[mi], 0, 0, 0);
                    accu[mi] = __builtin_amdgcn_mfma_f32_16x16x32_bf16(a1[mi], bu1, accu[mi], 0, 0, 0);
                }
                __builtin_amdgcn_s_setprio(0);
                __builtin_amdgcn_s_barrier();
                asm volatile("" ::: "memory");
            }
            // ---------- odd stage s = 2*s2+1 : read buf1 ----------
            {
                const char* at = abase + (size_t)s2 * 4096 + 2048;
                bf16x8 a0[10], a1[10];
#pragma unroll
                for (int mi = 0; mi < 10; ++mi)
                    a0[mi] = *(const bf16x8*)(at + aoff[mi]);
#pragma unroll
                for (int mi = 0; mi < 10; ++mi)
                    a1[mi] = *(const bf16x8*)(at + 1024 + aoff[mi]);
                bf16x8 bg0 = *(const bf16x8*)(&blds[8192 + srd]);
                bf16x8 bu0 = *(const bf16x8*)(&blds[8192 + srd + 2048]);
                bf16x8 bg1 = *(const bf16x8*)(&blds[12288 + srd]);
                bf16x8 bu1 = *(const bf16x8*)(&blds[12288 + srd + 2048]);
                if (s2 < 7) { G1_DEQW2(2*s2 + 2, PA); }
                if (s2 < 6) { G1_ISSUE2(2*s2 + 4, PA); }
                asm volatile("s_waitcnt lgkmcnt(0)" ::: "memory");
                __builtin_amdgcn_sched_barrier(0);
                __builtin_amdgcn_s_setprio(1);
#pragma unroll
                for (int mi = 0; mi < 10; ++mi) {
                    accg[mi] = __builtin_amdgcn_mfma_f32_16x16x32_bf16(a0[mi], bg0, accg[mi], 0, 0, 0);
                    accu[mi] = __builtin_amdgcn_mfma_f32_16x16x32_bf16(a0[mi], bu0, accu[mi], 0, 0, 0);
                }
#pragma unroll
                for (int mi = 0; mi < 10; ++mi) {
                    accg[mi] = __builtin_amdgcn_mfma_f32_16x16x32_bf16(a1[mi], bg1, accg[mi], 0, 0, 0);
                    accu[mi] = __builtin_amdgcn_mfma_f32_16x16x32_bf16(a1[mi], bu1, accu[mi], 0, 0, 0);
                }
                __builtin_amdgcn_s_setprio(0);
                __builtin_amdgcn_s_barrier();
                asm volatile("" ::: "memory");
            }
        }
        // epilogue: silu(gate)*up -> act_f fragment-major
#pragma unroll
        for (int mi = 0; mi < 10; ++mi) {
#pragma unroll
            for (int r = 0; r < 4; ++r) {
                int ml = mh * 160 + mi * 16 + lq * 4 + r;
                int m = tb + ml;
                if (m < npad) {
                    float gv = accg[mi][r], uv = accu[mi][r];
                    float av = gv / (1.f + __expf(-gv)) * uv;
                    int prow = pb + m;
                    size_t o = (size_t)(prow >> 4) * 90112 + (jcol >> 3) * 128
                             + (prow & 15) * 8 + (jcol & 7);
                    actf[o] = (unsigned short)f2bf(av);
                }
            }
        }
    }
#undef G1_ISSUE2
#undef G1_DEQW1
#undef G1_DEQW2
}

// ---------------------------------------------------- gemm2: act@w2 --------
// grid = E_*16dt*4seg = 512 blocks. Same raw-barrier counted-wait staging
// as gemm1. 44 K-steps = 22 stages of 2.
__global__ __launch_bounds__(256, 2) void gemm2_kernel(
    const unsigned short* __restrict__ actf, const int* __restrict__ w2q,
    const float* __restrict__ w2s, const int* __restrict__ cnt,
    const int* __restrict__ basep, float* __restrict__ y)
{
    __shared__ unsigned char blds[16384];
    int bid = blockIdx.x;
    int seg = bid & 3, dt = (bid >> 2) & 15, e = bid >> 6;
    int n = cnt[e];
    if (n <= 0) return;
    int npad = (n + 15) & ~15;
    int pb = basep[e];
    int tid = threadIdx.x, lane = tid & 63, w = tid >> 6;
    int l15 = lane & 15, lq = lane >> 4;
    int colg = w & 1, mh = w >> 1;
    int dcol = dt * 64 + colg * 32 + l15;      // second frag col = dcol + 16

    int col64 = tid & 63, kg = tid >> 6;
    int colb = dt * 64 + col64;
    const int*   gq  = w2q + ((size_t)e * 5632 + seg * 1408 + kg * 8) * 1024 + colb;
    const float* sqp = w2s + ((size_t)e * 44 + seg * 11) * 1024 + colb;
    unsigned swr = (unsigned)(col64 >> 4) * 1024 + (unsigned)(kg * 16 + (col64 & 15)) * 16;
    unsigned srd = (unsigned)(colg * 2) * 1024 + (unsigned)lane * 16;  // frag0; frag1 +1024

    int PA[16], PB[16];
    float sc = 0.f, oc = 0.f;

#define G2_ISSUE2(T, P)                                                     \
    { _Pragma("unroll")                                                     \
      for (int i_ = 0; i_ < 8; ++i_)                                        \
          P[i_] = gq[(size_t)((T) * 64 + i_) * 1024];                       \
      _Pragma("unroll")                                                     \
      for (int i_ = 0; i_ < 8; ++i_)                                        \
          P[8 + i_] = gq[(size_t)((T) * 64 + 32 + i_) * 1024]; }

#define G2_DEQW1(KS, P, O)                                                  \
    { if (((KS) & 3) == 0) { sc = sqp[(size_t)((KS) >> 2) * 1024];          \
                             oc = -8.f * sc; }                              \
      uint4 fr_;                                                            \
      fr_.x = pack2bf((float)P[(O)+0]*sc + oc, (float)P[(O)+1]*sc + oc);    \
      fr_.y = pack2bf((float)P[(O)+2]*sc + oc, (float)P[(O)+3]*sc + oc);    \
      fr_.z = pack2bf((float)P[(O)+4]*sc + oc, (float)P[(O)+5]*sc + oc);    \
      fr_.w = pack2bf((float)P[(O)+6]*sc + oc, (float)P[(O)+7]*sc + oc);    \
      *(uint4*)(&blds[((((KS) >> 1) & 1) * 8192) + (((KS) & 1) * 4096)      \
                      + swr]) = fr_; }

#define G2_DEQW2(T, P)  { G2_DEQW1((2*(T)), P, 0) G2_DEQW1((2*(T)+1), P, 8) }

    for (int tb = 0; tb < npad; tb += 320) {
        int aoff[10];
#pragma unroll
        for (int mi = 0; mi < 10; ++mi) {
            int R = tb + mh * 160 + mi * 16;
            R = min(R, npad - 16);
            aoff[mi] = ((pb + R) >> 4) * 180224;
        }
        const char* abase = (const char*)actf + seg * 45056 + lq * 256 + l15 * 16;

        f32x4 acc0[10], acc1[10];
#pragma unroll
        for (int mi = 0; mi < 10; ++mi) {
            acc0[mi] = (f32x4){0.f, 0.f, 0.f, 0.f};
            acc1[mi] = (f32x4){0.f, 0.f, 0.f, 0.f};
        }
        G2_ISSUE2(0, PA);
        G2_ISSUE2(1, PB);
        G2_DEQW2(0, PA);
        G2_ISSUE2(2, PA);
        asm volatile("s_waitcnt lgkmcnt(0)" ::: "memory");
        __builtin_amdgcn_s_barrier();
        asm volatile("" ::: "memory");

#pragma unroll 1
        for (int s2 = 0; s2 < 11; ++s2) {
            // ---------- even stage s = 2*s2 : read buf0 ----------
            {
                const char* at = abase + (size_t)s2 * 4096;
                bf16x8 a0[10], a1[10];
#pragma unroll
                for (int mi = 0; mi < 10; ++mi)
                    a0[mi] = *(const bf16x8*)(at + aoff[mi]);
#pragma unroll
                for (int mi = 0; mi < 10; ++mi)
                    a1[mi] = *(const bf16x8*)(at + 1024 + aoff[mi]);
                bf16x8 b00 = *(const bf16x8*)(&blds[srd]);
                bf16x8 b01 = *(const bf16x8*)(&blds[srd + 1024]);
                bf16x8 b10 = *(const bf16x8*)(&blds[4096 + srd]);
                bf16x8 b11 = *(const bf16x8*)(&blds[4096 + srd + 1024]);
                G2_DEQW2(2*s2 + 1, PB);
                if (s2 < 10) { G2_ISSUE2(2*s2 + 3, PB); }
                asm volatile("s_waitcnt lgkmcnt(0)" ::: "memory");
                __builtin_amdgcn_sched_barrier(0);
                __builtin_amdgcn_s_setprio(1);
#pragma unroll
                for (int mi = 0; mi < 10; ++mi) {
                    acc0[mi] = __builtin_amdgcn_mfma_f32_16x16x32_bf16(a0[mi], b00, acc0[mi], 0, 0, 0);
                    acc1[mi] = __builtin_amdgcn_mfma_f32_16x16x32_bf16(a0[mi], b01, acc1[mi], 0, 0, 0);
                }
#pragma unroll
                for (int mi = 0; mi < 10; ++mi) {
                    acc0[mi] = __builtin_amdgcn_mfma_f32_16x16x32_bf16(a1[mi], b10, acc0[mi], 0, 0, 0);
                    acc1[mi] = __builtin_amdgcn_mfma_f32_16x16x32_bf16(a1[mi], b11, acc1[mi], 0, 0, 0);
                }
                __builtin_amdgcn_s_setprio(0);
                __builtin_amdgcn_s_barrier();
                asm volatile("" ::: "memory");
            }
            // ---------- odd stage s = 2*s2+1 : read buf1 ----------
            {
                const char* at = abase + (size_t)s2 * 4096 + 2048;
                bf16x8 a0[10], a1[10];
#pragma unroll
                for (int mi = 0; mi < 10; ++mi)
                    a0[mi] = *(const bf16x8*)(at + aoff[mi]);
#pragma unroll
                for (int mi = 0; mi < 10; ++mi)
                    a1[mi] = *(const bf16x8*)(at + 1024 + aoff[mi]);
                bf16x8 b00 = *(const bf16x8*)(&blds[8192 + srd]);
                bf16x8 b01 = *(const bf16x8*)(&blds[8192 + srd + 1024]);
                bf16x8 b10 = *(const bf16x8*)(&blds[12288 + srd]);
                bf16x8 b11 = *(const bf16x8*)(&blds[12288 + srd + 1024]);
                if (s2 < 10) { G2_DEQW2(2*s2 + 2, PA); }
                if (s2 < 9)  { G2_ISSUE2(2*s2 + 4, PA); }
                asm volatile("s_waitcnt lgkmcnt(0)" ::: "memory");
                __builtin_amdgcn_sched_barrier(0);
                __builtin_amdgcn_s_setprio(1);
#pragma unroll
                for (int mi = 0; mi < 10; ++mi) {
                    acc0[mi] = __builtin_amdgcn_mfma_f32_16x16x32_bf16(a0[mi], b00, acc0[mi], 0, 0, 0);
                    acc1[mi] = __builtin_amdgcn_mfma_f32_16x16x32_bf16(a0[mi], b01, acc1[mi], 0, 0, 0);
                }
#pragma unroll
                for (int mi = 0; mi < 10; ++mi) {
                    acc0[mi] = __builtin_amdgcn_mfma_f32_16x16x32_bf16(a1[mi], b10, acc0[mi], 0, 0, 0);
                    acc1[mi] = __builtin_amdgcn_mfma_f32_16x16x32_bf16(a1[mi], b11, acc1[mi], 0, 0, 0);
                }
                __builtin_amdgcn_s_setprio(0);
                __builtin_amdgcn_s_barrier();
                asm volatile("" ::: "memory");
            }
        }
#pragma unroll
        for (int mi = 0; mi < 10; ++mi) {
#pragma unroll
            for (int r = 0; r < 4; ++r) {
                int m = tb + mh * 160 + mi * 16 + lq * 4 + r;
                if (m < n) {
                    float* yr = y + (size_t)seg * NPAD_MAX * 1024 + (size_t)(pb + m) * 1024;
                    yr[dcol]      = acc0[mi][r];
                    yr[dcol + 16] = acc1[mi][r];
                }
            }
        }
    }
#undef G2_ISSUE2
#undef G2_DEQW1
#undef G2_DEQW2
}

// --------------------------------------------------------------- combine ---
__global__ void combine_kernel(const float* __restrict__ y,
                               const int* __restrict__ eslot,
                               const float* __restrict__ tokw,
                               const int* __restrict__ basep,
                               float* __restrict__ out)
{
    int idx = blockIdx.x * blockDim.x + threadIdx.x;
    int t  = idx >> 8;
    int dc = idx & 255;
    int es0 = eslot[t * 2 + 0], es1 = eslot[t * 2 + 1];
    float w0 = tokw[t * 2 + 0], w1 = tokw[t * 2 + 1];
    int p0 = basep[es0 >> 10] + (es0 & 1023);
    int p1 = basep[es1 >> 10] + (es1 & 1023);
    const float4* y4 = (const float4*)y;
    float4 o = (float4){0.f, 0.f, 0.f, 0.f};
#pragma unroll
    for (int seg = 0; seg < 4; ++seg) {
        float4 a = y4[((size_t)seg * NPAD_MAX + p0) * 256 + dc];
        float4 b = y4[((size_t)seg * NPAD_MAX + p1) * 256 + dc];
        o.x += w0 * a.x + w1 * b.x;
        o.y += w0 * a.y + w1 * b.y;
        o.z += w0 * a.z + w1 * b.z;
        o.w += w0 * a.w + w1 * b.w;
    }
    ((float4*)out)[idx] = o;
}

// ---------------------------------------------------------------- launch ---
extern "C" void kernel_launch(void* const* d_in, const int* in_sizes, int n_in,
                              void* d_out, int out_size, void* d_ws, size_t ws_size,
                              hipStream_t stream)
{
    const float* x    = (const float*)d_in[0];
    const float* gate = (const float*)d_in[1];
    const int*   w1q  = (const int*)d_in[2];
    const int*   w2q  = (const int*)d_in[3];
    const float* w1s  = (const float*)d_in[4];
    const float* w2s  = (const float*)d_in[5];
    float* out = (float*)d_out;
    int*   wsi = (int*)d_ws;
    float* wsf = (float*)d_ws;

    int*   cnt   = wsi + WS_CNT;
    int*   basep = wsi + WS_BASEP;
    int*   eslot = wsi + WS_ESLOT;
    float* tokw  = wsf + WS_TOKW;
    int*   etok  = wsi + WS_ETOK;
    unsigned short* actf = (unsigned short*)((char*)d_ws + WS_ACTF_B);
    unsigned short* xgf  = (unsigned short*)((char*)d_ws + WS_XGF_B);
    float*          y    = (float*)((char*)d_ws + WS_Y_B);

    routing_kernel<<<1, 1024, 0, stream>>>(gate, cnt, basep, eslot, tokw, etok);
    gather_cast_kernel<<<E_ * 64, 256, 0, stream>>>(x, cnt, basep, etok, xgf);
    gemm1_kernel<<<E_ * 176, 256, 0, stream>>>(xgf, w1q, w1s, cnt, basep, actf);
    gemm2_kernel<<<E_ * 16 * 4, 256, 0, stream>>>(actf, w2q, w2s, cnt, basep, y);
    combine_kernel<<<(T_ * D_ / 4) / 256, 256, 0, stream>>>(y, eslot, tokw, basep, out);
}

// Round 3
// 741.375 us; speedup vs baseline: 1.1390x; 1.1390x over previous
//
#include <hip/hip_runtime.h>
#include <cstdint>
#include <cstddef>

#define E_ 8
#define T_ 1024
#define D_ 1024
#define I_ 5632
#define TWO_I_ 11264
#define NPAD_MAX 2176                 /* 2048 + 8*16 */
#define NGRP_MAX 136

// ws layout (bytes): int tables in [0,64K), then act_f, then xg_f, y overlays xg_f
#define WS_ACTF_B 65536
#define WS_XGF_B  (65536 + 24510464)              /* act_f = 136*180224      */
#define WS_Y_B    WS_XGF_B                        /* y overlays dead xg_f    */
// int-table offsets (units of 4 B)
#define WS_CNT   0
#define WS_BASEP 8
#define WS_ESLOT 16
#define WS_TOKW  2064
#define WS_ETOK  4112

typedef __attribute__((ext_vector_type(8))) __bf16 bf16x8;
typedef __attribute__((ext_vector_type(4))) float  f32x4;

__device__ __forceinline__ unsigned f2bf(float f) {
    unsigned u = __float_as_uint(f);
    u += 0x7fffu + ((u >> 16) & 1u);
    return u >> 16;
}
__device__ __forceinline__ unsigned pack2bf(float f0, float f1) {
    unsigned a0 = __float_as_uint(f0); a0 += 0x7fffu + ((a0 >> 16) & 1u);
    unsigned a1 = __float_as_uint(f1); a1 += 0x7fffu + ((a1 >> 16) & 1u);
    return (a0 >> 16) | (a1 & 0xffff0000u);
}

// ---------------------------------------------------------------- routing ---
__global__ void routing_kernel(const float* __restrict__ gate,
                               int* cnt, int* basep, int* eslot,
                               float* tokw, int* etok)
{
    int t = threadIdx.x;
    if (t < E_) cnt[t] = 0;
    __syncthreads();
    float g[E_];
#pragma unroll
    for (int e = 0; e < E_; ++e) g[e] = gate[t * E_ + e];
    int i0 = 0; float p0 = g[0];
#pragma unroll
    for (int e = 1; e < E_; ++e) if (g[e] > p0) { p0 = g[e]; i0 = e; }
    int i1 = -1; float p1 = -1e30f;
#pragma unroll
    for (int e = 0; e < E_; ++e) if (e != i0 && g[e] > p1) { p1 = g[e]; i1 = e; }
    float w0 = 1.0f / (1.0f + expf(p1 - p0));
    float w1 = 1.0f - w0;
    int s0 = atomicAdd(&cnt[i0], 1);
    int s1 = atomicAdd(&cnt[i1], 1);
    etok[i0 * T_ + s0] = t;
    etok[i1 * T_ + s1] = t;
    eslot[t * 2 + 0] = i0 * T_ + s0;  tokw[t * 2 + 0] = w0;
    eslot[t * 2 + 1] = i1 * T_ + s1;  tokw[t * 2 + 1] = w1;
    __syncthreads();
    if (t == 0) {
        int r = 0;
#pragma unroll
        for (int e = 0; e < E_; ++e) { basep[e] = r; r += (cnt[e] + 15) & ~15; }
    }
}

// ------------------- gather x rows, cast bf16, fragment-major swizzle -------
__global__ void gather_cast_kernel(const float* __restrict__ x,
                                   const int* __restrict__ cnt,
                                   const int* __restrict__ basep,
                                   const int* __restrict__ etok,
                                   unsigned short* __restrict__ xgf)
{
    int e = blockIdx.x >> 6, g = blockIdx.x & 63;
    int n = cnt[e];
    if (g * 16 >= n) return;
    int tid = threadIdx.x;
    int row = g * 16 + (tid & 15);
    row = min(row, n - 1);
    int tok = etok[e * T_ + row];
    const float* xr = x + (size_t)tok * D_;
    unsigned short* dst = xgf + ((size_t)(basep[e] >> 4) + g) * 16384;
#pragma unroll
    for (int it = 0; it < 8; ++it) {
        int c = it * 16 + (tid >> 4);          // k-chunk 0..127
        float4 v0 = *(const float4*)(xr + c * 8);
        float4 v1 = *(const float4*)(xr + c * 8 + 4);
        uint4 h;
        h.x = pack2bf(v0.x, v0.y); h.y = pack2bf(v0.z, v0.w);
        h.z = pack2bf(v1.x, v1.y); h.w = pack2bf(v1.z, v1.w);
        *(uint4*)(dst + c * 128 + (tid & 15) * 8) = h;
    }
}

// ------------------------------------------------- gemm1: xg@w1 + silu -----
// grid = E_*176, block 8 waves (512 thr). Wave tile M=80 (5 frags) x
// (16 gate + 16 up) -> 40 acc regs -> 4 waves/SIMD occupancy.
// B path: BK=32 LDS-staged dequant, 4-stage-deep register prefetch of q,
// raw s_barrier + lgkmcnt(0) only (vmcnt never drained -> prefetch spans
// barriers). A loads issued BEFORE B prefetch each stage so A's counted
// vmcnt waits leave the B prefetch in flight.
__global__ __launch_bounds__(512, 4) void gemm1_kernel(
    const unsigned short* __restrict__ xgf, const int* __restrict__ w1q,
    const float* __restrict__ w1s, const int* __restrict__ cnt,
    const int* __restrict__ basep, unsigned short* __restrict__ actf)
{
    __shared__ unsigned char blds[2][4096];
    int cg = blockIdx.x % 176, e = blockIdx.x / 176;
    int n = cnt[e];
    if (n <= 0) return;
    int npad = (n + 15) & ~15;
    int pb = basep[e];
    int tid = threadIdx.x, lane = tid & 63, w = tid >> 6;
    int l15 = lane & 15, lq = lane >> 4;
    int colg = w & 1, mh = w >> 1;          // mh 0..3
    int jcol = cg * 32 + colg * 16 + l15;

    // staging role: 512 thr cover 64 cols x 32 k per stage (4 dwords each)
    int col64 = lane, kg = w;               // kg 0..7 -> k-subgroup of 4
    int jb = (col64 < 32) ? (cg * 32 + col64) : (I_ + cg * 32 + (col64 - 32));
    const int*   gq  = w1q + ((size_t)e * 1024 + kg * 4) * TWO_I_ + jb;
    const float* sqp = w1s + (size_t)e * 8 * TWO_I_ + jb;
    // LDS frag layout per 4KB stage slot: [c=col64/16][lane'=(k/8)*16+col%16][k%8]
    unsigned swr = (unsigned)(col64 >> 4) * 1024
                 + (unsigned)((kg >> 1) * 16 + (col64 & 15)) * 16
                 + (unsigned)(kg & 1) * 8;
    unsigned srd = (unsigned)colg * 1024 + (unsigned)lane * 16;  // gate; up +2048

    int P0[4], P1[4], P2[4], P3[4];
    float S0, S1, S2, S3;

#define G1_ISSUE(S, P, SS)                                                  \
    { _Pragma("unroll")                                                     \
      for (int i_ = 0; i_ < 4; ++i_)                                        \
          P[i_] = gq[(size_t)((S) * 32 + i_) * TWO_I_];                     \
      SS = sqp[(size_t)((S) >> 2) * TWO_I_]; }

#define G1_DEQW(S, P, SS)                                                   \
    { float oc_ = -8.f * SS;                                                \
      uint2 fr_;                                                            \
      fr_.x = pack2bf((float)P[0]*SS + oc_, (float)P[1]*SS + oc_);          \
      fr_.y = pack2bf((float)P[2]*SS + oc_, (float)P[3]*SS + oc_);          \
      *(uint2*)(&blds[(S) & 1][swr]) = fr_; }

    for (int tb = 0; tb < npad; tb += 320) {
        int aoff[5];
#pragma unroll
        for (int mi = 0; mi < 5; ++mi) {
            int R = tb + mh * 80 + mi * 16;
            R = min(R, npad - 16);
            aoff[mi] = ((pb + R) >> 4) * 32768;
        }
        const char* abase = (const char*)xgf + lq * 256 + l15 * 16;

        f32x4 accg[5], accu[5];
#pragma unroll
        for (int mi = 0; mi < 5; ++mi) {
            accg[mi] = (f32x4){0.f, 0.f, 0.f, 0.f};
            accu[mi] = (f32x4){0.f, 0.f, 0.f, 0.f};
        }
        G1_ISSUE(0, P0, S0);
        G1_ISSUE(1, P1, S1);
        G1_ISSUE(2, P2, S2);
        G1_ISSUE(3, P3, S3);
        G1_DEQW(0, P0, S0);
        G1_ISSUE(4, P0, S0);
        asm volatile("s_waitcnt lgkmcnt(0)" ::: "memory");
        __builtin_amdgcn_s_barrier();
        asm volatile("" ::: "memory");

#pragma unroll 4
        for (int s = 0; s < 32; ++s) {
            // A loads first: their counted vmcnt waits leave B prefetch alive
            const char* at = abase + (size_t)s * 1024;
            bf16x8 a[5];
#pragma unroll
            for (int mi = 0; mi < 5; ++mi)
                a[mi] = *(const bf16x8*)(at + aoff[mi]);
            // dequant stage s+1 into back buffer; refill slot with stage s+5
            if (s + 1 < 32) {
                const int sl = (s + 1) & 3;
                if (sl == 0)      { G1_DEQW(s+1, P0, S0); if (s+5 < 32) { G1_ISSUE(s+5, P0, S0); } }
                else if (sl == 1) { G1_DEQW(s+1, P1, S1); if (s+5 < 32) { G1_ISSUE(s+5, P1, S1); } }
                else if (sl == 2) { G1_DEQW(s+1, P2, S2); if (s+5 < 32) { G1_ISSUE(s+5, P2, S2); } }
                else              { G1_DEQW(s+1, P3, S3); if (s+5 < 32) { G1_ISSUE(s+5, P3, S3); } }
            }
            bf16x8 bg = *(const bf16x8*)(&blds[s & 1][srd]);
            bf16x8 bu = *(const bf16x8*)(&blds[s & 1][srd + 2048]);
#pragma unroll
            for (int mi = 0; mi < 5; ++mi) {
                accg[mi] = __builtin_amdgcn_mfma_f32_16x16x32_bf16(a[mi], bg, accg[mi], 0, 0, 0);
                accu[mi] = __builtin_amdgcn_mfma_f32_16x16x32_bf16(a[mi], bu, accu[mi], 0, 0, 0);
            }
            asm volatile("s_waitcnt lgkmcnt(0)" ::: "memory");
            __builtin_amdgcn_s_barrier();
            asm volatile("" ::: "memory");
        }
        // epilogue: silu(gate)*up -> act_f fragment-major
#pragma unroll
        for (int mi = 0; mi < 5; ++mi) {
#pragma unroll
            for (int r = 0; r < 4; ++r) {
                int ml = mh * 80 + mi * 16 + lq * 4 + r;
                int m = tb + ml;
                if (m < npad) {
                    float gv = accg[mi][r], uv = accu[mi][r];
                    float av = gv / (1.f + __expf(-gv)) * uv;
                    int prow = pb + m;
                    size_t o = (size_t)(prow >> 4) * 90112 + (jcol >> 3) * 128
                             + (prow & 15) * 8 + (jcol & 7);
                    actf[o] = (unsigned short)f2bf(av);
                }
            }
        }
    }
#undef G1_ISSUE
#undef G1_DEQW
}

// ---------------------------------------------------- gemm2: act@w2 --------
// grid = E_*16dt*4seg = 512 blocks x 512 thr. Same 8-wave BK=32 structure:
// wave M=80 x 32 cols (2 frags), K/seg = 1408 (44 stages).
__global__ __launch_bounds__(512, 4) void gemm2_kernel(
    const unsigned short* __restrict__ actf, const int* __restrict__ w2q,
    const float* __restrict__ w2s, const int* __restrict__ cnt,
    const int* __restrict__ basep, float* __restrict__ y)
{
    __shared__ unsigned char blds[2][4096];
    int bid = blockIdx.x;
    int seg = bid & 3, dt = (bid >> 2) & 15, e = bid >> 6;
    int n = cnt[e];
    if (n <= 0) return;
    int npad = (n + 15) & ~15;
    int pb = basep[e];
    int tid = threadIdx.x, lane = tid & 63, w = tid >> 6;
    int l15 = lane & 15, lq = lane >> 4;
    int colg = w & 1, mh = w >> 1;          // mh 0..3
    int dcol = dt * 64 + colg * 32 + l15;   // second frag col = dcol + 16

    int col64 = lane, kg = w;
    int colb = dt * 64 + col64;
    const int*   gq  = w2q + ((size_t)e * 5632 + seg * 1408 + kg * 4) * 1024 + colb;
    const float* sqp = w2s + ((size_t)e * 44 + seg * 11) * 1024 + colb;
    unsigned swr = (unsigned)(col64 >> 4) * 1024
                 + (unsigned)((kg >> 1) * 16 + (col64 & 15)) * 16
                 + (unsigned)(kg & 1) * 8;
    unsigned srd = (unsigned)colg * 2048 + (unsigned)lane * 16;  // frag0; frag1 +1024

    int P0[4], P1[4], P2[4], P3[4];
    float S0, S1, S2, S3;

#define G2_ISSUE(S, P, SS)                                                  \
    { _Pragma("unroll")                                                     \
      for (int i_ = 0; i_ < 4; ++i_)                                        \
          P[i_] = gq[(size_t)((S) * 32 + i_) * 1024];                       \
      SS = sqp[(size_t)((S) >> 2) * 1024]; }

#define G2_DEQW(S, P, SS)                                                   \
    { float oc_ = -8.f * SS;                                                \
      uint2 fr_;                                                            \
      fr_.x = pack2bf((float)P[0]*SS + oc_, (float)P[1]*SS + oc_);          \
      fr_.y = pack2bf((float)P[2]*SS + oc_, (float)P[3]*SS + oc_);          \
      *(uint2*)(&blds[(S) & 1][swr]) = fr_; }

    for (int tb = 0; tb < npad; tb += 320) {
        int aoff[5];
#pragma unroll
        for (int mi = 0; mi < 5; ++mi) {
            int R = tb + mh * 80 + mi * 16;
            R = min(R, npad - 16);
            aoff[mi] = ((pb + R) >> 4) * 180224;
        }
        const char* abase = (const char*)actf + seg * 45056 + lq * 256 + l15 * 16;

        f32x4 acc0[5], acc1[5];
#pragma unroll
        for (int mi = 0; mi < 5; ++mi) {
            acc0[mi] = (f32x4){0.f, 0.f, 0.f, 0.f};
            acc1[mi] = (f32x4){0.f, 0.f, 0.f, 0.f};
        }
        G2_ISSUE(0, P0, S0);
        G2_ISSUE(1, P1, S1);
        G2_ISSUE(2, P2, S2);
        G2_ISSUE(3, P3, S3);
        G2_DEQW(0, P0, S0);
        G2_ISSUE(4, P0, S0);
        asm volatile("s_waitcnt lgkmcnt(0)" ::: "memory");
        __builtin_amdgcn_s_barrier();
        asm volatile("" ::: "memory");

#pragma unroll 4
        for (int s = 0; s < 44; ++s) {
            const char* at = abase + (size_t)s * 1024;
            bf16x8 a[5];
#pragma unroll
            for (int mi = 0; mi < 5; ++mi)
                a[mi] = *(const bf16x8*)(at + aoff[mi]);
            if (s + 1 < 44) {
                const int sl = (s + 1) & 3;
                if (sl == 0)      { G2_DEQW(s+1, P0, S0); if (s+5 < 44) { G2_ISSUE(s+5, P0, S0); } }
                else if (sl == 1) { G2_DEQW(s+1, P1, S1); if (s+5 < 44) { G2_ISSUE(s+5, P1, S1); } }
                else if (sl == 2) { G2_DEQW(s+1, P2, S2); if (s+5 < 44) { G2_ISSUE(s+5, P2, S2); } }
                else              { G2_DEQW(s+1, P3, S3); if (s+5 < 44) { G2_ISSUE(s+5, P3, S3); } }
            }
            bf16x8 b0 = *(const bf16x8*)(&blds[s & 1][srd]);
            bf16x8 b1 = *(const bf16x8*)(&blds[s & 1][srd + 1024]);
#pragma unroll
            for (int mi = 0; mi < 5; ++mi) {
                acc0[mi] = __builtin_amdgcn_mfma_f32_16x16x32_bf16(a[mi], b0, acc0[mi], 0, 0, 0);
                acc1[mi] = __builtin_amdgcn_mfma_f32_16x16x32_bf16(a[mi], b1, acc1[mi], 0, 0, 0);
            }
            asm volatile("s_waitcnt lgkmcnt(0)" ::: "memory");
            __builtin_amdgcn_s_barrier();
            asm volatile("" ::: "memory");
        }
#pragma unroll
        for (int mi = 0; mi < 5; ++mi) {
#pragma unroll
            for (int r = 0; r < 4; ++r) {
                int m = tb + mh * 80 + mi * 16 + lq * 4 + r;
                if (m < n) {
                    float* yr = y + (size_t)seg * NPAD_MAX * 1024 + (size_t)(pb + m) * 1024;
                    yr[dcol]      = acc0[mi][r];
                    yr[dcol + 16] = acc1[mi][r];
                }
            }
        }
    }
#undef G2_ISSUE
#undef G2_DEQW
}

// --------------------------------------------------------------- combine ---
__global__ void combine_kernel(const float* __restrict__ y,
                               const int* __restrict__ eslot,
                               const float* __restrict__ tokw,
                               const int* __restrict__ basep,
                               float* __restrict__ out)
{
    int idx = blockIdx.x * blockDim.x + threadIdx.x;
    int t  = idx >> 8;
    int dc = idx & 255;
    int es0 = eslot[t * 2 + 0], es1 = eslot[t * 2 + 1];
    float w0 = tokw[t * 2 + 0], w1 = tokw[t * 2 + 1];
    int p0 = basep[es0 >> 10] + (es0 & 1023);
    int p1 = basep[es1 >> 10] + (es1 & 1023);
    const float4* y4 = (const float4*)y;
    float4 o = (float4){0.f, 0.f, 0.f, 0.f};
#pragma unroll
    for (int seg = 0; seg < 4; ++seg) {
        float4 a = y4[((size_t)seg * NPAD_MAX + p0) * 256 + dc];
        float4 b = y4[((size_t)seg * NPAD_MAX + p1) * 256 + dc];
        o.x += w0 * a.x + w1 * b.x;
        o.y += w0 * a.y + w1 * b.y;
        o.z += w0 * a.z + w1 * b.z;
        o.w += w0 * a.w + w1 * b.w;
    }
    ((float4*)out)[idx] = o;
}

// ---------------------------------------------------------------- launch ---
extern "C" void kernel_launch(void* const* d_in, const int* in_sizes, int n_in,
                              void* d_out, int out_size, void* d_ws, size_t ws_size,
                              hipStream_t stream)
{
    const float* x    = (const float*)d_in[0];
    const float* gate = (const float*)d_in[1];
    const int*   w1q  = (const int*)d_in[2];
    const int*   w2q  = (const int*)d_in[3];
    const float* w1s  = (const float*)d_in[4];
    const float* w2s  = (const float*)d_in[5];
    float* out = (float*)d_out;
    int*   wsi = (int*)d_ws;
    float* wsf = (float*)d_ws;

    int*   cnt   = wsi + WS_CNT;
    int*   basep = wsi + WS_BASEP;
    int*   eslot = wsi + WS_ESLOT;
    float* tokw  = wsf + WS_TOKW;
    int*   etok  = wsi + WS_ETOK;
    unsigned short* actf = (unsigned short*)((char*)d_ws + WS_ACTF_B);
    unsigned short* xgf  = (unsigned short*)((char*)d_ws + WS_XGF_B);
    float*          y    = (float*)((char*)d_ws + WS_Y_B);

    routing_kernel<<<1, 1024, 0, stream>>>(gate, cnt, basep, eslot, tokw, etok);
    gather_cast_kernel<<<E_ * 64, 256, 0, stream>>>(x, cnt, basep, etok, xgf);
    gemm1_kernel<<<E_ * 176, 512, 0, stream>>>(xgf, w1q, w1s, cnt, basep, actf);
    gemm2_kernel<<<E_ * 16 * 4, 512, 0, stream>>>(actf, w2q, w2s, cnt, basep, y);
    combine_kernel<<<(T_ * D_ / 4) / 256, 256, 0, stream>>>(y, eslot, tokw, basep, out);
}